// Round 1
// baseline (632.833 us; speedup 1.0000x reference)
//
#include <hip/hip_runtime.h>
#include <math.h>

#define T_HIST 256
#define T_BIG 1024
#define NBINS 4096
#define CH (NBINS / T_HIST) /* 16 */
#define GCAP 512
#define EQCAP 32

struct RowState {
  float m;          // row max of x = logits/t
  float S;          // sum exp(x-m) over full row
  float target;     // p * S (mode 1)
  int mode;         // 0 = top-k path (1<=k<=256), 1 = top-p-only
  int k;            // effective k (mode 0)
  unsigned prefix;  // resolved high bits of boundary key
  int cnt_above;    // # elements with key above current bin
  float exp_above;  // sum exp over those
  unsigned vstar;   // final boundary key
  float Z2;         // final softmax denominator (sum over kept)
  int r;            // # copies of boundary value kept
  int eqn;          // entries in eq[]
  int eq[EQCAP];    // indices of kept boundary-valued tokens
};

struct ScanAux {
  unsigned ccnt[T_HIST];
  float cesum[T_HIST];
  unsigned csufc[T_HIST];
  float csufe[T_HIST];
  int candbin[T_HIST];
  unsigned candca[T_HIST];
  float candea[T_HIST];
  int fbbin[T_HIST];
  unsigned fbca[T_HIST];
  float fbea[T_HIST];
};

__device__ __forceinline__ unsigned f2key(float f) {
  unsigned u = __float_as_uint(f);
  return u ^ ((u >> 31) ? 0xFFFFFFFFu : 0x80000000u);
}
__device__ __forceinline__ float key2f(unsigned k) {
  unsigned u = (k & 0x80000000u) ? (k ^ 0x80000000u) : ~k;
  return __uint_as_float(u);
}

// Block-cooperative: find the bin (descending key order) where the running
// count (mode 0) or running exp-sum (mode 1) crosses its target.
__device__ void scan_select(const unsigned* cnt, const float* esum, ScanAux* ax,
                            RowState* rs, float S, float p, int level) {
  const int tid = threadIdx.x;
  const int mode = rs->mode;
  const unsigned ca0 = (level == 0) ? 0u : (unsigned)rs->cnt_above;
  const float ea0 = (level == 0) ? 0.f : rs->exp_above;
  float target = 0.f;
  if (mode == 1) target = (level == 0) ? (p * S) : rs->target;
  const int need = (mode == 0) ? (rs->k - (int)ca0) : 0;

  {
    unsigned cc = 0; float ce = 0.f;
    int base = tid * CH;
    for (int j = 0; j < CH; ++j) { cc += cnt[base + j]; ce += esum[base + j]; }
    ax->ccnt[tid] = cc; ax->cesum[tid] = ce;
  }
  __syncthreads();
  if (tid == 0) {
    unsigned rc = 0; float re = 0.f;
    for (int c = T_HIST - 1; c >= 0; --c) {
      ax->csufc[c] = rc; ax->csufe[c] = re;
      rc += ax->ccnt[c]; re += ax->cesum[c];
    }
  }
  __syncthreads();
  {
    int base = tid * CH;
    unsigned rc = ax->csufc[tid]; float re = ax->csufe[tid];
    int best = -1; unsigned bca = 0; float bea = 0.f;
    int fb = -1; unsigned fca = 0; float fea = 0.f;
    for (int b = base + CH - 1; b >= base; --b) {
      unsigned c = cnt[b];
      bool cross;
      if (mode == 0) cross = (c > 0) && ((int)(rc + c) >= need);
      else cross = (c > 0) && (ea0 + (re + esum[b]) >= target);
      if (cross && best < 0) { best = b; bca = rc; bea = re; }
      if (c > 0) { fb = b; fca = rc; fea = re; }
      rc += c; re += esum[b];
    }
    ax->candbin[tid] = best; ax->candca[tid] = bca; ax->candea[tid] = bea;
    ax->fbbin[tid] = fb; ax->fbca[tid] = fca; ax->fbea[tid] = fea;
  }
  __syncthreads();
  if (tid == 0) {
    int bsel = -1; unsigned ca = 0; float ea = 0.f;
    for (int c = 0; c < T_HIST; ++c) {
      int b = ax->candbin[c];
      if (b > bsel) { bsel = b; ca = ax->candca[c]; ea = ax->candea[c]; }
    }
    if (bsel < 0) {
      // no crossing (mode 1 keep-nearly-all): lowest nonempty bin
      for (int c = 0; c < T_HIST; ++c) {
        int b = ax->fbbin[c];
        if (b >= 0 && (bsel < 0 || b < bsel)) { bsel = b; ca = ax->fbca[c]; ea = ax->fbea[c]; }
      }
    }
    if (bsel < 0) bsel = 0;
    rs->prefix = (level == 0) ? (unsigned)bsel : ((rs->prefix << 12) | (unsigned)bsel);
    rs->cnt_above = (int)(ca0 + ca);
    rs->exp_above = ea0 + ea;
    rs->target = target;
  }
}

__global__ __launch_bounds__(T_BIG) void k1_rowmax(const float* __restrict__ logits,
                                                   const float* __restrict__ temps,
                                                   const int* __restrict__ topks,
                                                   RowState* __restrict__ st, int V) {
  const int row = blockIdx.x;
  const float t = temps[row];
  const float* lr = logits + (size_t)row * V;
  const float4* l4 = (const float4*)lr;
  const int n4 = V >> 2;
  float mx = -INFINITY;
  for (int i = threadIdx.x; i < n4; i += T_BIG) {
    float4 v = l4[i];
    mx = fmaxf(mx, fmaxf(fmaxf(v.x / t, v.y / t), fmaxf(v.z / t, v.w / t)));
  }
  for (int i = (n4 << 2) + threadIdx.x; i < V; i += T_BIG) mx = fmaxf(mx, lr[i] / t);
  __shared__ float sm[T_BIG];
  sm[threadIdx.x] = mx;
  __syncthreads();
  for (int s = T_BIG >> 1; s > 0; s >>= 1) {
    if (threadIdx.x < (unsigned)s) sm[threadIdx.x] = fmaxf(sm[threadIdx.x], sm[threadIdx.x + s]);
    __syncthreads();
  }
  if (threadIdx.x == 0) {
    RowState* rs = &st[row];
    rs->m = sm[0];
    int k = topks[row];
    if (k >= 1 && k <= 256 && k < V) { rs->mode = 0; rs->k = k; }
    else { rs->mode = 1; rs->k = 0; }
  }
}

__global__ __launch_bounds__(T_HIST) void k2_hist1(const float* __restrict__ logits,
                                                   const float* __restrict__ temps,
                                                   const float* __restrict__ topps,
                                                   RowState* __restrict__ st, int V) {
  const int row = blockIdx.x;
  RowState* rs = &st[row];
  __shared__ unsigned cnt[NBINS];
  __shared__ float esum[NBINS];
  __shared__ float ssum[T_HIST];
  __shared__ ScanAux ax;
  for (int i = threadIdx.x; i < NBINS; i += T_HIST) { cnt[i] = 0; esum[i] = 0.f; }
  __syncthreads();
  const float t = temps[row];
  const float m = rs->m;
  const float* lr = logits + (size_t)row * V;
  const float4* l4 = (const float4*)lr;
  const int n4 = V >> 2;
  float ls = 0.f;
  for (int i = threadIdx.x; i < n4; i += T_HIST) {
    float4 v = l4[i];
    float xs[4] = {v.x / t, v.y / t, v.z / t, v.w / t};
#pragma unroll
    for (int j = 0; j < 4; ++j) {
      float x = xs[j];
      unsigned key = f2key(x);
      float e = expf(x - m);
      atomicAdd(&cnt[key >> 20], 1u);
      atomicAdd(&esum[key >> 20], e);
      ls += e;
    }
  }
  for (int i = (n4 << 2) + threadIdx.x; i < V; i += T_HIST) {
    float x = lr[i] / t;
    unsigned key = f2key(x);
    float e = expf(x - m);
    atomicAdd(&cnt[key >> 20], 1u);
    atomicAdd(&esum[key >> 20], e);
    ls += e;
  }
  ssum[threadIdx.x] = ls;
  __syncthreads();
  for (int s = T_HIST >> 1; s > 0; s >>= 1) {
    if (threadIdx.x < (unsigned)s) ssum[threadIdx.x] += ssum[threadIdx.x + s];
    __syncthreads();
  }
  float S = ssum[0];
  if (threadIdx.x == 0) rs->S = S;
  scan_select(cnt, esum, &ax, rs, S, topps[row], 0);
}

__global__ __launch_bounds__(T_HIST) void k3_hist2(const float* __restrict__ logits,
                                                   const float* __restrict__ temps,
                                                   RowState* __restrict__ st, int V) {
  const int row = blockIdx.x;
  RowState* rs = &st[row];
  __shared__ unsigned cnt[NBINS];
  __shared__ float esum[NBINS];
  __shared__ ScanAux ax;
  for (int i = threadIdx.x; i < NBINS; i += T_HIST) { cnt[i] = 0; esum[i] = 0.f; }
  __syncthreads();
  const float t = temps[row];
  const float m = rs->m;
  const unsigned pfx = rs->prefix;  // 12-bit
  const float* lr = logits + (size_t)row * V;
  const float4* l4 = (const float4*)lr;
  const int n4 = V >> 2;
  for (int i = threadIdx.x; i < n4; i += T_HIST) {
    float4 v = l4[i];
    float xs[4] = {v.x / t, v.y / t, v.z / t, v.w / t};
#pragma unroll
    for (int j = 0; j < 4; ++j) {
      unsigned key = f2key(xs[j]);
      if ((key >> 20) == pfx) {
        atomicAdd(&cnt[(key >> 8) & 0xFFFu], 1u);
        atomicAdd(&esum[(key >> 8) & 0xFFFu], expf(xs[j] - m));
      }
    }
  }
  for (int i = (n4 << 2) + threadIdx.x; i < V; i += T_HIST) {
    float x = lr[i] / t;
    unsigned key = f2key(x);
    if ((key >> 20) == pfx) {
      atomicAdd(&cnt[(key >> 8) & 0xFFFu], 1u);
      atomicAdd(&esum[(key >> 8) & 0xFFFu], expf(x - m));
    }
  }
  __syncthreads();
  scan_select(cnt, esum, &ax, rs, rs->S, 0.f, 1);
}

__global__ __launch_bounds__(T_HIST) void k4_refine(const float* __restrict__ logits,
                                                    const float* __restrict__ temps,
                                                    const float* __restrict__ topps,
                                                    RowState* __restrict__ st, int V) {
  const int row = blockIdx.x;
  RowState* rs = &st[row];
  __shared__ unsigned cnt[256];
  cnt[threadIdx.x] = 0;
  __syncthreads();
  const float t = temps[row];
  const unsigned pfx = rs->prefix;  // 24-bit
  const float* lr = logits + (size_t)row * V;
  const float4* l4 = (const float4*)lr;
  const int n4 = V >> 2;
  for (int i = threadIdx.x; i < n4; i += T_HIST) {
    float4 v = l4[i];
    float xs[4] = {v.x / t, v.y / t, v.z / t, v.w / t};
#pragma unroll
    for (int j = 0; j < 4; ++j) {
      unsigned key = f2key(xs[j]);
      if ((key >> 8) == pfx) atomicAdd(&cnt[key & 0xFFu], 1u);
    }
  }
  for (int i = (n4 << 2) + threadIdx.x; i < V; i += T_HIST) {
    unsigned key = f2key(lr[i] / t);
    if ((key >> 8) == pfx) atomicAdd(&cnt[key & 0xFFu], 1u);
  }
  __syncthreads();
  if (threadIdx.x == 0) {
    if (rs->mode == 0) {
      int need = rs->k - rs->cnt_above;
      int rc = 0; int bsel = -1;
      for (int b = 255; b >= 0; --b) {
        int c = (int)cnt[b];
        if (c > 0 && rc + c >= need) { bsel = b; break; }
        rc += c;
      }
      if (bsel < 0) { for (int b = 0; b < 256; ++b) if (cnt[b] > 0) { bsel = b; break; } }
      if (bsel < 0) bsel = 0;
      rs->vstar = (pfx << 8) | (unsigned)bsel;  // T_k; K5 finishes exactly
    } else {
      const float m = rs->m;
      const float S = rs->S;
      const float p = topps[row];
      float run_n = rs->exp_above / S;  // normalized cumulative (pre-bin)
      float run_u = rs->exp_above;      // unnormalized (for Z2)
      const int have_above = (rs->cnt_above > 0);
      unsigned lastkey = 0u; int lastr = 0; int anykept = 0;
      unsigned vsel = 0u; int rsel = -1;
      for (int b = 255; b >= 0; --b) {
        int c = (int)cnt[b];
        if (c == 0) continue;
        unsigned key = (pfx << 8) | (unsigned)b;
        float v = key2f(key);
        float e = expf(v - m);
        float en = e / S;
        int kept = 0;
        for (int q = 0; q < c; ++q) {
          float nn = run_n + en;
          if (nn < p) { run_n = nn; run_u += e; kept++; } else break;
        }
        if (kept == c) { lastkey = key; lastr = c; anykept = 1; continue; }
        if (kept > 0) { vsel = key; rsel = kept; }
        else if (anykept) { vsel = lastkey; rsel = lastr; }
        else if (have_above) { vsel = key; rsel = 0; }      // kept = strictly above
        else { vsel = key; rsel = 1; run_u += e; }          // forced top-1
        break;
      }
      if (rsel < 0) {  // never failed -> keep everything down to lowest key
        if (anykept) { vsel = lastkey; rsel = lastr; }
        else { vsel = (pfx << 8); rsel = have_above ? 0 : 1; }
      }
      rs->vstar = vsel; rs->r = rsel; rs->Z2 = run_u;
    }
  }
}

__global__ __launch_bounds__(T_HIST) void k5_gather(const float* __restrict__ logits,
                                                    const float* __restrict__ temps,
                                                    const float* __restrict__ topps,
                                                    RowState* __restrict__ st, int V) {
  const int row = blockIdx.x;
  RowState* rs = &st[row];
  __shared__ float gv[GCAP];
  __shared__ int gi[GCAP];
  __shared__ float sv[GCAP];
  __shared__ int si[GCAP];
  __shared__ int gcount;
  if (threadIdx.x == 0) gcount = 0;
  __syncthreads();
  const float t = temps[row];
  const int mode = rs->mode;
  const unsigned vk = rs->vstar;
  const float* lr = logits + (size_t)row * V;
  const float4* l4 = (const float4*)lr;
  const int n4 = V >> 2;
  for (int i = threadIdx.x; i < n4; i += T_HIST) {
    float4 v4 = l4[i];
    float xs[4] = {v4.x / t, v4.y / t, v4.z / t, v4.w / t};
#pragma unroll
    for (int j = 0; j < 4; ++j) {
      unsigned key = f2key(xs[j]);
      bool take = (mode == 0) ? (key >= vk) : (key == vk);
      if (take) {
        int slot = atomicAdd(&gcount, 1);
        if (slot < GCAP) { gv[slot] = xs[j]; gi[slot] = i * 4 + j; }
      }
    }
  }
  for (int i = (n4 << 2) + threadIdx.x; i < V; i += T_HIST) {
    float x = lr[i] / t;
    unsigned key = f2key(x);
    bool take = (mode == 0) ? (key >= vk) : (key == vk);
    if (take) {
      int slot = atomicAdd(&gcount, 1);
      if (slot < GCAP) { gv[slot] = x; gi[slot] = i; }
    }
  }
  __syncthreads();
  int g = gcount; if (g > GCAP) g = GCAP;
  // rank sort by (value desc, index asc) -- exactly argsort(-x) stable order
  for (int i = threadIdx.x; i < g; i += T_HIST) {
    float v = gv[i]; int ix = gi[i];
    int rank = 0;
    for (int j = 0; j < g; ++j) {
      float vj = gv[j]; int ij = gi[j];
      if (vj > v || (vj == v && ij < ix)) rank++;
    }
    sv[rank] = v; si[rank] = ix;
  }
  __syncthreads();
  if (threadIdx.x == 0) {
    if (mode == 0) {
      const float m = rs->m;
      const float p = topps[row];
      int keff = rs->k; if (keff > g) keff = g;
      if (g > 0 && keff > 0) {
        float Zk = 0.f;
        for (int j = 0; j < keff; ++j) Zk += expf(sv[j] - m);
        float c = 0.f; int J = 0;
        for (int j = 0; j < keff; ++j) {
          float pr = expf(sv[j] - m) / Zk;
          c = c + pr;
          if (c < p) J = J + 1; else break;
        }
        if (J < 1) J = 1;
        float Z2 = 0.f;
        for (int j = 0; j < J; ++j) Z2 += expf(sv[j] - m);
        float vs = sv[J - 1];
        rs->vstar = f2key(vs);
        rs->Z2 = Z2;
        int eqn = 0;
        for (int j = 0; j < J; ++j)
          if (sv[j] == vs && eqn < EQCAP) rs->eq[eqn++] = si[j];
        rs->eqn = eqn; rs->r = eqn;
      } else { rs->Z2 = 1.f; rs->eqn = 0; }
    } else {
      int eqn = rs->r;
      if (eqn > g) eqn = g;
      if (eqn > EQCAP) eqn = EQCAP;
      if (eqn < 0) eqn = 0;
      for (int j = 0; j < eqn; ++j) rs->eq[j] = si[j];  // ascending index
      rs->eqn = eqn;
    }
  }
}

__global__ __launch_bounds__(T_BIG) void k6_race(const float* __restrict__ logits,
                                                 const float* __restrict__ temps,
                                                 const float* __restrict__ noise,
                                                 const RowState* __restrict__ st,
                                                 int* __restrict__ out, int V) {
  const int row = blockIdx.x;
  const RowState* rs = &st[row];
  __shared__ int eqs[EQCAP];
  __shared__ int seqn;
  if (threadIdx.x == 0) {
    int n = rs->eqn; if (n > EQCAP) n = EQCAP; if (n < 0) n = 0;
    seqn = n;
    for (int i = 0; i < n; ++i) eqs[i] = rs->eq[i];
  }
  __syncthreads();
  const float t = temps[row];
  const float m = rs->m;
  const float Z2 = rs->Z2;
  const unsigned vk = rs->vstar;
  const int eqn = seqn;
  const float* lr = logits + (size_t)row * V;
  const float* ur = noise + (size_t)row * V;
  const float4* l4 = (const float4*)lr;
  const float4* u4 = (const float4*)ur;
  const int n4 = V >> 2;
  float best = -1.f; int bidx = 0;
  for (int i = threadIdx.x; i < n4; i += T_BIG) {
    float4 xv = l4[i];
    float4 uv = u4[i];
    float xs[4] = {xv.x / t, xv.y / t, xv.z / t, xv.w / t};
    float us[4] = {uv.x, uv.y, uv.z, uv.w};
#pragma unroll
    for (int j = 0; j < 4; ++j) {
      float x = xs[j];
      unsigned key = f2key(x);
      bool kept = key > vk;
      if (!kept && key == vk) {
        int idx = i * 4 + j;
        for (int e = 0; e < eqn; ++e) if (eqs[e] == idx) { kept = true; break; }
      }
      if (kept) {
        float pr = expf(x - m) / Z2;
        float q = fmaxf(-logf(us[j]), 1e-10f);
        float rt = pr / q;
        if (rt > best) { best = rt; bidx = i * 4 + j; }
      }
    }
  }
  for (int i = (n4 << 2) + threadIdx.x; i < V; i += T_BIG) {
    float x = lr[i] / t;
    unsigned key = f2key(x);
    bool kept = key > vk;
    if (!kept && key == vk) {
      for (int e = 0; e < eqn; ++e) if (eqs[e] == i) { kept = true; break; }
    }
    if (kept) {
      float pr = expf(x - m) / Z2;
      float q = fmaxf(-logf(ur[i]), 1e-10f);
      float rt = pr / q;
      if (rt > best) { best = rt; bidx = i; }
    }
  }
  __shared__ float rv[T_BIG];
  __shared__ int ri[T_BIG];
  rv[threadIdx.x] = best; ri[threadIdx.x] = bidx;
  __syncthreads();
  for (int s = T_BIG >> 1; s > 0; s >>= 1) {
    if (threadIdx.x < (unsigned)s) {
      float ov = rv[threadIdx.x + s]; int oi = ri[threadIdx.x + s];
      if (ov > rv[threadIdx.x] || (ov == rv[threadIdx.x] && oi < ri[threadIdx.x])) {
        rv[threadIdx.x] = ov; ri[threadIdx.x] = oi;
      }
    }
    __syncthreads();
  }
  if (threadIdx.x == 0) out[row] = ri[0];
}

extern "C" void kernel_launch(void* const* d_in, const int* in_sizes, int n_in,
                              void* d_out, int out_size, void* d_ws, size_t ws_size,
                              hipStream_t stream) {
  const float* logits = (const float*)d_in[0];
  const float* temps = (const float*)d_in[1];
  const int* topks = (const int*)d_in[2];
  const float* topps = (const float*)d_in[3];
  const float* noise = (const float*)d_in[4];
  int* out = (int*)d_out;
  const int B = in_sizes[1];
  const int V = in_sizes[0] / B;
  RowState* st = (RowState*)d_ws;
  (void)n_in; (void)out_size; (void)ws_size;

  k1_rowmax<<<B, T_BIG, 0, stream>>>(logits, temps, topks, st, V);
  k2_hist1<<<B, T_HIST, 0, stream>>>(logits, temps, topps, st, V);
  k3_hist2<<<B, T_HIST, 0, stream>>>(logits, temps, st, V);
  k4_refine<<<B, T_HIST, 0, stream>>>(logits, temps, topps, st, V);
  k5_gather<<<B, T_HIST, 0, stream>>>(logits, temps, topps, st, V);
  k6_race<<<B, T_BIG, 0, stream>>>(logits, temps, noise, st, out, V);
}

// Round 2
// 405.881 us; speedup vs baseline: 1.5592x; 1.5592x over previous
//
#include <hip/hip_runtime.h>
#include <math.h>

#define SA 8
#define NB 4096
#define TB 256
#define CH (NB / TB) /* 16 */
#define GCAP 1024
#define MAXM1 16
#define EQC 64

typedef unsigned u32;
typedef unsigned long long u64;

struct State {
  float m, S, target, Z2;
  int mode, k, cnt_above;
  float exp_above;
  u32 prefix, vstar;
  int m1, r, eqn;
  int eq[EQC];
};

struct ScanAux {
  u32 ccnt[TB]; float cesum[TB];
  u32 csufc[TB]; float csufe[TB];
  int candbin[TB]; u32 candca[TB]; float candea[TB];
  int fbbin[TB]; u32 fbca[TB]; float fbea[TB];
};

__device__ __forceinline__ u32 f2key(float f) {
  u32 u = __float_as_uint(f);
  return u ^ ((u >> 31) ? 0xFFFFFFFFu : 0x80000000u);
}
__device__ __forceinline__ float key2f(u32 k) {
  u32 u = (k & 0x80000000u) ? (k ^ 0x80000000u) : ~k;
  return __uint_as_float(u);
}

// verbatim-equivalent of R1's proven scan_select (used for mode-1 rows only)
__device__ void scan_select(const u32* cnt, const float* esum, ScanAux* ax,
                            State* rs, float S, float p, int level) {
  const int tid = threadIdx.x;
  const int mode = rs->mode;
  const u32 ca0 = (level == 0) ? 0u : (u32)rs->cnt_above;
  const float ea0 = (level == 0) ? 0.f : rs->exp_above;
  float target = 0.f;
  if (mode == 1) target = (level == 0) ? (p * S) : rs->target;
  const int need = (mode == 0) ? (rs->k - (int)ca0) : 0;

  {
    u32 cc = 0; float ce = 0.f;
    int base = tid * CH;
    for (int j = 0; j < CH; ++j) { cc += cnt[base + j]; ce += esum[base + j]; }
    ax->ccnt[tid] = cc; ax->cesum[tid] = ce;
  }
  __syncthreads();
  if (tid == 0) {
    u32 rc = 0; float re = 0.f;
    for (int c = TB - 1; c >= 0; --c) {
      ax->csufc[c] = rc; ax->csufe[c] = re;
      rc += ax->ccnt[c]; re += ax->cesum[c];
    }
  }
  __syncthreads();
  {
    int base = tid * CH;
    u32 rc = ax->csufc[tid]; float re = ax->csufe[tid];
    int best = -1; u32 bca = 0; float bea = 0.f;
    int fb = -1; u32 fca = 0; float fea = 0.f;
    for (int b = base + CH - 1; b >= base; --b) {
      u32 c = cnt[b];
      bool cross;
      if (mode == 0) cross = (c > 0) && ((int)(rc + c) >= need);
      else cross = (c > 0) && (ea0 + (re + esum[b]) >= target);
      if (cross && best < 0) { best = b; bca = rc; bea = re; }
      if (c > 0) { fb = b; fca = rc; fea = re; }
      rc += c; re += esum[b];
    }
    ax->candbin[tid] = best; ax->candca[tid] = bca; ax->candea[tid] = bea;
    ax->fbbin[tid] = fb; ax->fbca[tid] = fca; ax->fbea[tid] = fea;
  }
  __syncthreads();
  if (tid == 0) {
    int bsel = -1; u32 ca = 0; float ea = 0.f;
    for (int c = 0; c < TB; ++c) {
      int b = ax->candbin[c];
      if (b > bsel) { bsel = b; ca = ax->candca[c]; ea = ax->candea[c]; }
    }
    if (bsel < 0) {
      for (int c = 0; c < TB; ++c) {
        int b = ax->fbbin[c];
        if (b >= 0 && (bsel < 0 || b < bsel)) { bsel = b; ca = ax->fbca[c]; ea = ax->fbea[c]; }
      }
    }
    if (bsel < 0) bsel = 0;
    rs->prefix = (level == 0) ? (u32)bsel : ((rs->prefix << 12) | (u32)bsel);
    rs->cnt_above = (int)(ca0 + ca);
    rs->exp_above = ea0 + ea;
    rs->target = target;
  }
}

__global__ void kz(u32* __restrict__ w, size_t nwords) {
  size_t i = (size_t)blockIdx.x * blockDim.x + threadIdx.x;
  size_t stride = (size_t)gridDim.x * blockDim.x;
  for (; i < nwords; i += stride) w[i] = 0;
}

// fused: per-row max (atomicMax on key) + 4096-bin count hist (split SA ways)
__global__ __launch_bounds__(TB) void kA(const float* __restrict__ logits,
                                         const float* __restrict__ temps,
                                         u32* __restrict__ hist,
                                         u32* __restrict__ maxkey, int V) {
  const int row = blockIdx.x, seg = blockIdx.y, tid = threadIdx.x;
  __shared__ u32 cnt[NB];
  __shared__ float sm[TB];
  for (int i = tid; i < NB; i += TB) cnt[i] = 0;
  __syncthreads();
  const float t = temps[row];
  const float* lr = logits + (size_t)row * V;
  const float4* l4 = (const float4*)lr;
  const int n4 = V >> 2;
  const int q0 = (int)((long long)seg * n4 / SA);
  const int q1 = (int)((long long)(seg + 1) * n4 / SA);
  float mx = -INFINITY;
  for (int i = q0 + tid; i < q1; i += TB) {
    float4 v = l4[i];
    float xs[4] = {v.x / t, v.y / t, v.z / t, v.w / t};
#pragma unroll
    for (int j = 0; j < 4; ++j) {
      atomicAdd(&cnt[f2key(xs[j]) >> 20], 1u);
      mx = fmaxf(mx, xs[j]);
    }
  }
  if (seg == SA - 1)
    for (int i = (n4 << 2) + tid; i < V; i += TB) {
      float x = lr[i] / t;
      atomicAdd(&cnt[f2key(x) >> 20], 1u);
      mx = fmaxf(mx, x);
    }
  sm[tid] = mx;
  __syncthreads();
  for (int s = TB >> 1; s > 0; s >>= 1) {
    if (tid < s) sm[tid] = fmaxf(sm[tid], sm[tid + s]);
    __syncthreads();
  }
  if (tid == 0) atomicMax(&maxkey[row], f2key(sm[0]));
  for (int b = tid; b < NB; b += TB) {
    u32 c = cnt[b];
    if (c) atomicAdd(&hist[(size_t)row * NB + b], c);
  }
}

// per-row: mode decision + mode-0 level-0 crossing bin -> gather threshold
__global__ __launch_bounds__(TB) void kB(const u32* __restrict__ hist,
                                         const int* __restrict__ topks,
                                         const u32* __restrict__ maxkey,
                                         State* __restrict__ st,
                                         u32* __restrict__ nm1, int V) {
  const int row = blockIdx.x, tid = threadIdx.x;
  State* rs = &st[row];
  __shared__ u32 h[NB];
  __shared__ u32 cs[TB];
  __shared__ int bb[TB];
  for (int i = tid; i < NB; i += TB) h[i] = hist[(size_t)row * NB + i];
  __syncthreads();
  int k = topks[row];
  int mode = (k >= 1 && k < V) ? 0 : 1;
  if (tid == 0) {
    rs->m = key2f(maxkey[row]);
    rs->mode = mode; rs->k = k;
    rs->eqn = 0; rs->r = 0;
    if (mode == 1) rs->m1 = (int)atomicAdd(nm1, 1u);
  }
  u32 cc = 0;
  const int base = tid * CH;
  for (int j = 0; j < CH; ++j) cc += h[base + j];
  cs[tid] = cc;
  __syncthreads();
  if (tid == 0) {
    u32 rc = 0;
    for (int c = TB - 1; c >= 0; --c) { u32 t2 = cs[c]; cs[c] = rc; rc += t2; }
  }
  __syncthreads();
  {
    u32 rc = cs[tid];
    int best = -1;
    for (int b = base + CH - 1; b >= base; --b) {
      u32 c = h[b];
      if (c && best < 0 && (int)(rc + c) >= k) best = b;
      rc += c;
    }
    bb[tid] = best;
  }
  __syncthreads();
  if (tid == 0 && mode == 0) {
    int bsel = -1;
    for (int c = 0; c < TB; ++c) if (bb[c] > bsel) bsel = bb[c];
    if (bsel < 0) { for (int b2 = 0; b2 < NB; ++b2) if (h[b2]) { bsel = b2; break; } }
    if (bsel < 0) bsel = 0;
    rs->vstar = ((u32)bsel) << 20;  // mode-0 gather threshold T0
  }
}

// mode-1 only: level-0 count+esum hist + S partials
__global__ __launch_bounds__(TB) void kC(const float* __restrict__ logits,
                                         const float* __restrict__ temps,
                                         const State* __restrict__ st,
                                         float* __restrict__ Sparts,
                                         u32* __restrict__ m1c0,
                                         float* __restrict__ m1e0, int V) {
  const int row = blockIdx.x, seg = blockIdx.y, tid = threadIdx.x;
  const State* rs = &st[row];
  if (rs->mode != 1) return;
  const int m1 = rs->m1;
  if (m1 >= MAXM1) return;
  __shared__ u32 c0[NB];
  __shared__ float e0[NB];
  __shared__ float ss[TB];
  for (int i = tid; i < NB; i += TB) { c0[i] = 0; e0[i] = 0.f; }
  __syncthreads();
  const float t = temps[row];
  const float m = rs->m;
  const float* lr = logits + (size_t)row * V;
  const float4* l4 = (const float4*)lr;
  const int n4 = V >> 2;
  const int q0 = (int)((long long)seg * n4 / SA);
  const int q1 = (int)((long long)(seg + 1) * n4 / SA);
  float ls = 0.f;
  for (int i = q0 + tid; i < q1; i += TB) {
    float4 v = l4[i];
    float xs[4] = {v.x / t, v.y / t, v.z / t, v.w / t};
#pragma unroll
    for (int j = 0; j < 4; ++j) {
      u32 key = f2key(xs[j]);
      float e = expf(xs[j] - m);
      atomicAdd(&c0[key >> 20], 1u);
      atomicAdd(&e0[key >> 20], e);
      ls += e;
    }
  }
  if (seg == SA - 1)
    for (int i = (n4 << 2) + tid; i < V; i += TB) {
      float x = lr[i] / t;
      u32 key = f2key(x);
      float e = expf(x - m);
      atomicAdd(&c0[key >> 20], 1u);
      atomicAdd(&e0[key >> 20], e);
      ls += e;
    }
  ss[tid] = ls;
  __syncthreads();
  for (int s = TB >> 1; s > 0; s >>= 1) {
    if (tid < s) ss[tid] += ss[tid + s];
    __syncthreads();
  }
  if (tid == 0) Sparts[m1 * SA + seg] = ss[0];
  for (int b = tid; b < NB; b += TB) {
    if (c0[b]) {
      atomicAdd(&m1c0[(size_t)m1 * NB + b], c0[b]);
      atomicAdd(&m1e0[(size_t)m1 * NB + b], e0[b]);
    }
  }
}

__global__ __launch_bounds__(TB) void kC2(const float* __restrict__ topps,
                                          const float* __restrict__ Sparts,
                                          const u32* __restrict__ m1c0,
                                          const float* __restrict__ m1e0,
                                          State* __restrict__ st) {
  const int row = blockIdx.x, tid = threadIdx.x;
  State* rs = &st[row];
  if (rs->mode != 1) return;
  const int m1 = rs->m1;
  if (m1 >= MAXM1) return;
  __shared__ u32 cnt[NB];
  __shared__ float esum[NB];
  __shared__ ScanAux ax;
  for (int i = tid; i < NB; i += TB) {
    cnt[i] = m1c0[(size_t)m1 * NB + i];
    esum[i] = m1e0[(size_t)m1 * NB + i];
  }
  __syncthreads();
  float S = 0.f;
  for (int j = 0; j < SA; ++j) S += Sparts[m1 * SA + j];
  if (tid == 0) rs->S = S;
  scan_select(cnt, esum, &ax, rs, S, topps[row], 0);
}

// mode-1 only: level-1 (middle 12 bits)
__global__ __launch_bounds__(TB) void kD(const float* __restrict__ logits,
                                         const float* __restrict__ temps,
                                         const State* __restrict__ st,
                                         u32* __restrict__ m1c1,
                                         float* __restrict__ m1e1, int V) {
  const int row = blockIdx.x, seg = blockIdx.y, tid = threadIdx.x;
  const State* rs = &st[row];
  if (rs->mode != 1) return;
  const int m1 = rs->m1;
  if (m1 >= MAXM1) return;
  __shared__ u32 c1[NB];
  __shared__ float e1[NB];
  for (int i = tid; i < NB; i += TB) { c1[i] = 0; e1[i] = 0.f; }
  __syncthreads();
  const float t = temps[row];
  const float m = rs->m;
  const u32 pfx = rs->prefix;  // 12-bit
  const float* lr = logits + (size_t)row * V;
  const float4* l4 = (const float4*)lr;
  const int n4 = V >> 2;
  const int q0 = (int)((long long)seg * n4 / SA);
  const int q1 = (int)((long long)(seg + 1) * n4 / SA);
  for (int i = q0 + tid; i < q1; i += TB) {
    float4 v = l4[i];
    float xs[4] = {v.x / t, v.y / t, v.z / t, v.w / t};
#pragma unroll
    for (int j = 0; j < 4; ++j) {
      u32 key = f2key(xs[j]);
      if ((key >> 20) == pfx) {
        atomicAdd(&c1[(key >> 8) & 0xFFFu], 1u);
        atomicAdd(&e1[(key >> 8) & 0xFFFu], expf(xs[j] - m));
      }
    }
  }
  if (seg == SA - 1)
    for (int i = (n4 << 2) + tid; i < V; i += TB) {
      float x = lr[i] / t;
      u32 key = f2key(x);
      if ((key >> 20) == pfx) {
        atomicAdd(&c1[(key >> 8) & 0xFFFu], 1u);
        atomicAdd(&e1[(key >> 8) & 0xFFFu], expf(x - m));
      }
    }
  __syncthreads();
  for (int b = tid; b < NB; b += TB) {
    if (c1[b]) {
      atomicAdd(&m1c1[(size_t)m1 * NB + b], c1[b]);
      atomicAdd(&m1e1[(size_t)m1 * NB + b], e1[b]);
    }
  }
}

__global__ __launch_bounds__(TB) void kD2(const u32* __restrict__ m1c1,
                                          const float* __restrict__ m1e1,
                                          State* __restrict__ st) {
  const int row = blockIdx.x, tid = threadIdx.x;
  State* rs = &st[row];
  if (rs->mode != 1) return;
  const int m1 = rs->m1;
  if (m1 >= MAXM1) return;
  __shared__ u32 cnt[NB];
  __shared__ float esum[NB];
  __shared__ ScanAux ax;
  for (int i = tid; i < NB; i += TB) {
    cnt[i] = m1c1[(size_t)m1 * NB + i];
    esum[i] = m1e1[(size_t)m1 * NB + i];
  }
  __syncthreads();
  scan_select(cnt, esum, &ax, rs, rs->S, 0.f, 1);
}

// mode-1 only: final 8-bit count hist
__global__ __launch_bounds__(TB) void kE(const float* __restrict__ logits,
                                         const float* __restrict__ temps,
                                         const State* __restrict__ st,
                                         u32* __restrict__ m1c2, int V) {
  const int row = blockIdx.x, seg = blockIdx.y, tid = threadIdx.x;
  const State* rs = &st[row];
  if (rs->mode != 1) return;
  const int m1 = rs->m1;
  if (m1 >= MAXM1) return;
  __shared__ u32 c2[256];
  c2[tid] = 0;
  __syncthreads();
  const float t = temps[row];
  const u32 pfx = rs->prefix;  // 24-bit
  const float* lr = logits + (size_t)row * V;
  const float4* l4 = (const float4*)lr;
  const int n4 = V >> 2;
  const int q0 = (int)((long long)seg * n4 / SA);
  const int q1 = (int)((long long)(seg + 1) * n4 / SA);
  for (int i = q0 + tid; i < q1; i += TB) {
    float4 v = l4[i];
    float xs[4] = {v.x / t, v.y / t, v.z / t, v.w / t};
#pragma unroll
    for (int j = 0; j < 4; ++j) {
      u32 key = f2key(xs[j]);
      if ((key >> 8) == pfx) atomicAdd(&c2[key & 0xFFu], 1u);
    }
  }
  if (seg == SA - 1)
    for (int i = (n4 << 2) + tid; i < V; i += TB) {
      u32 key = f2key(lr[i] / t);
      if ((key >> 8) == pfx) atomicAdd(&c2[key & 0xFFu], 1u);
    }
  __syncthreads();
  if (c2[tid]) atomicAdd(&m1c2[(size_t)m1 * 256 + tid], c2[tid]);
}

// mode-1 only: exact per-copy cumsum replay (verbatim R1 k4 mode-1 branch)
__global__ __launch_bounds__(TB) void kE2(const float* __restrict__ topps,
                                          const u32* __restrict__ m1c2,
                                          State* __restrict__ st) {
  const int row = blockIdx.x;
  State* rs = &st[row];
  if (rs->mode != 1) return;
  const int m1 = rs->m1;
  if (m1 >= MAXM1) return;
  if (threadIdx.x != 0) return;
  const u32 pfx = rs->prefix;
  const float m = rs->m;
  const float S = rs->S;
  const float p = topps[row];
  float run_n = rs->exp_above / S;
  float run_u = rs->exp_above;
  const int have_above = (rs->cnt_above > 0);
  u32 lastkey = 0u; int lastr = 0; int anykept = 0;
  u32 vsel = 0u; int rsel = -1;
  for (int b = 255; b >= 0; --b) {
    int c = (int)m1c2[(size_t)m1 * 256 + b];
    if (c == 0) continue;
    u32 key = (pfx << 8) | (u32)b;
    float v = key2f(key);
    float e = expf(v - m);
    float en = e / S;
    int kept = 0;
    for (int q = 0; q < c; ++q) {
      float nn = run_n + en;
      if (nn < p) { run_n = nn; run_u += e; kept++; } else break;
    }
    if (kept == c) { lastkey = key; lastr = c; anykept = 1; continue; }
    if (kept > 0) { vsel = key; rsel = kept; }
    else if (anykept) { vsel = lastkey; rsel = lastr; }
    else if (have_above) { vsel = key; rsel = 0; }
    else { vsel = key; rsel = 1; run_u += e; }
    break;
  }
  if (rsel < 0) {
    if (anykept) { vsel = lastkey; rsel = lastr; }
    else { vsel = (pfx << 8); rsel = have_above ? 0 : 1; }
  }
  rs->vstar = vsel; rs->r = rsel; rs->Z2 = run_u;
}

// gather candidates: mode-0 key >= T0; mode-1 key == vstar
__global__ __launch_bounds__(TB) void kG(const float* __restrict__ logits,
                                         const float* __restrict__ temps,
                                         const State* __restrict__ st,
                                         u32* __restrict__ gcnt,
                                         float* __restrict__ candv,
                                         int* __restrict__ candi, int V) {
  const int row = blockIdx.x, seg = blockIdx.y, tid = threadIdx.x;
  const State* rs = &st[row];
  const int mode = rs->mode;
  const u32 vk = rs->vstar;
  const float t = temps[row];
  const float* lr = logits + (size_t)row * V;
  const float4* l4 = (const float4*)lr;
  const int n4 = V >> 2;
  const int q0 = (int)((long long)seg * n4 / SA);
  const int q1 = (int)((long long)(seg + 1) * n4 / SA);
  for (int i = q0 + tid; i < q1; i += TB) {
    float4 v = l4[i];
    float xs[4] = {v.x / t, v.y / t, v.z / t, v.w / t};
#pragma unroll
    for (int j = 0; j < 4; ++j) {
      u32 key = f2key(xs[j]);
      bool take = (mode == 0) ? (key >= vk) : (key == vk);
      if (take) {
        u32 slot = atomicAdd(&gcnt[row], 1u);
        if (slot < GCAP) {
          candv[(size_t)row * GCAP + slot] = xs[j];
          candi[(size_t)row * GCAP + slot] = i * 4 + j;
        }
      }
    }
  }
  if (seg == SA - 1)
    for (int i = (n4 << 2) + tid; i < V; i += TB) {
      float x = lr[i] / t;
      u32 key = f2key(x);
      bool take = (mode == 0) ? (key >= vk) : (key == vk);
      if (take) {
        u32 slot = atomicAdd(&gcnt[row], 1u);
        if (slot < GCAP) {
          candv[(size_t)row * GCAP + slot] = x;
          candi[(size_t)row * GCAP + slot] = i;
        }
      }
    }
}

// solve: exact reference replay on sorted candidates; mode-0 also runs the race
__global__ __launch_bounds__(TB) void kH(const float* __restrict__ topps,
                                         const float* __restrict__ noise,
                                         const u32* __restrict__ gcnt,
                                         const float* __restrict__ candv,
                                         const int* __restrict__ candi,
                                         State* __restrict__ st,
                                         int* __restrict__ out, int V) {
  const int row = blockIdx.x, tid = threadIdx.x;
  State* rs = &st[row];
  __shared__ float gv[GCAP]; __shared__ int gi[GCAP];
  __shared__ float sv[GCAP]; __shared__ int si[GCAP];
  __shared__ float rr[TB]; __shared__ int ri[TB];
  __shared__ int sJ; __shared__ float sZ2;
  int g = (int)gcnt[row]; if (g > GCAP) g = GCAP;
  for (int i = tid; i < g; i += TB) {
    gv[i] = candv[(size_t)row * GCAP + i];
    gi[i] = candi[(size_t)row * GCAP + i];
  }
  __syncthreads();
  // rank sort by (value desc, index asc) == stable argsort(-x)
  for (int i = tid; i < g; i += TB) {
    float v = gv[i]; int ix = gi[i];
    int rank = 0;
    for (int j = 0; j < g; ++j) {
      float vj = gv[j]; int ij = gi[j];
      if (vj > v || (vj == v && ij < ix)) rank++;
    }
    sv[rank] = v; si[rank] = ix;
  }
  __syncthreads();
  const float m = rs->m;
  const float p = topps[row];
  if (rs->mode == 0) {
    if (tid == 0) {
      int keff = rs->k; if (keff > g) keff = g;
      int J = 1; float Z2 = 1.f;
      if (g > 0 && keff > 0) {
        float Zk = 0.f;
        for (int j = 0; j < keff; ++j) Zk += expf(sv[j] - m);
        float c = 0.f; J = 0;
        for (int j = 0; j < keff; ++j) {
          float pr = expf(sv[j] - m) / Zk;
          c += pr;
          if (c < p) J++; else break;
        }
        if (J < 1) J = 1;
        Z2 = 0.f;
        for (int j = 0; j < J; ++j) Z2 += expf(sv[j] - m);
      }
      sJ = J; sZ2 = Z2;
    }
    __syncthreads();
    const int J = sJ; const float Z2 = sZ2;
    float best = -1.f; int bidx = 0x7FFFFFFF;
    for (int j = tid; j < J && j < g; j += TB) {
      int ix = si[j];
      float u = noise[(size_t)row * V + ix];
      float q = fmaxf(-logf(u), 1e-10f);
      float pr = expf(sv[j] - m) / Z2;
      float rt = pr / q;
      if (rt > best || (rt == best && ix < bidx)) { best = rt; bidx = ix; }
    }
    rr[tid] = best; ri[tid] = bidx;
    __syncthreads();
    for (int s = TB >> 1; s > 0; s >>= 1) {
      if (tid < s) {
        float ov = rr[tid + s]; int oi = ri[tid + s];
        if (ov > rr[tid] || (ov == rr[tid] && oi < ri[tid])) { rr[tid] = ov; ri[tid] = oi; }
      }
      __syncthreads();
    }
    if (tid == 0) out[row] = ri[0];
  } else {
    if (tid == 0) {
      int eqn = rs->r;
      if (eqn > g) eqn = g;
      if (eqn > EQC) eqn = EQC;
      if (eqn < 0) eqn = 0;
      for (int j = 0; j < eqn; ++j) rs->eq[j] = si[j];  // idx asc among equal values
      rs->eqn = eqn;
    }
  }
}

// mode-1 only: race over full row, packed (ratio_key, ~idx) atomicMax
__global__ __launch_bounds__(TB) void kI(const float* __restrict__ logits,
                                         const float* __restrict__ temps,
                                         const float* __restrict__ noise,
                                         const State* __restrict__ st,
                                         u64* __restrict__ rpack, int V) {
  const int row = blockIdx.x, seg = blockIdx.y, tid = threadIdx.x;
  const State* rs = &st[row];
  if (rs->mode != 1) return;
  __shared__ int eqs[EQC]; __shared__ int seqn;
  __shared__ float rr[TB]; __shared__ int ri[TB];
  if (tid == 0) {
    int n = rs->eqn; if (n > EQC) n = EQC; if (n < 0) n = 0;
    seqn = n;
    for (int i = 0; i < n; ++i) eqs[i] = rs->eq[i];
  }
  __syncthreads();
  const float t = temps[row];
  const float m = rs->m;
  const float Z2 = rs->Z2;
  const u32 vk = rs->vstar;
  const int eqn = seqn;
  const float* lr = logits + (size_t)row * V;
  const float* ur = noise + (size_t)row * V;
  const float4* l4 = (const float4*)lr;
  const float4* u4 = (const float4*)ur;
  const int n4 = V >> 2;
  const int q0 = (int)((long long)seg * n4 / SA);
  const int q1 = (int)((long long)(seg + 1) * n4 / SA);
  float best = -1.f; int bidx = 0x7FFFFFFF;
  for (int i = q0 + tid; i < q1; i += TB) {
    float4 xv = l4[i];
    float4 uv = u4[i];
    float xs[4] = {xv.x / t, xv.y / t, xv.z / t, xv.w / t};
    float us[4] = {uv.x, uv.y, uv.z, uv.w};
#pragma unroll
    for (int j = 0; j < 4; ++j) {
      u32 key = f2key(xs[j]);
      bool kept = key > vk;
      if (!kept && key == vk) {
        int idx = i * 4 + j;
        for (int e = 0; e < eqn; ++e) if (eqs[e] == idx) { kept = true; break; }
      }
      if (kept) {
        float pr = expf(xs[j] - m) / Z2;
        float q = fmaxf(-logf(us[j]), 1e-10f);
        float rt = pr / q;
        int idx = i * 4 + j;
        if (rt > best || (rt == best && idx < bidx)) { best = rt; bidx = idx; }
      }
    }
  }
  if (seg == SA - 1)
    for (int i = (n4 << 2) + tid; i < V; i += TB) {
      float x = lr[i] / t;
      u32 key = f2key(x);
      bool kept = key > vk;
      if (!kept && key == vk) {
        for (int e = 0; e < eqn; ++e) if (eqs[e] == i) { kept = true; break; }
      }
      if (kept) {
        float pr = expf(x - m) / Z2;
        float q = fmaxf(-logf(ur[i]), 1e-10f);
        float rt = pr / q;
        if (rt > best || (rt == best && i < bidx)) { best = rt; bidx = i; }
      }
    }
  rr[tid] = best; ri[tid] = bidx;
  __syncthreads();
  for (int s = TB >> 1; s > 0; s >>= 1) {
    if (tid < s) {
      float ov = rr[tid + s]; int oi = ri[tid + s];
      if (ov > rr[tid] || (ov == rr[tid] && oi < ri[tid])) { rr[tid] = ov; ri[tid] = oi; }
    }
    __syncthreads();
  }
  if (tid == 0 && rr[0] >= 0.f) {
    u64 pk = ((u64)f2key(rr[0]) << 32) | (u64)(0xFFFFFFFFu - (u32)ri[0]);
    atomicMax(&rpack[row], pk);
  }
}

__global__ void kJ(const State* __restrict__ st, const u64* __restrict__ rpack,
                   int* __restrict__ out, int B) {
  int i = blockIdx.x * blockDim.x + threadIdx.x;
  if (i < B && st[i].mode == 1)
    out[i] = (int)(0xFFFFFFFFu - (u32)(rpack[i] & 0xFFFFFFFFull));
}

extern "C" void kernel_launch(void* const* d_in, const int* in_sizes, int n_in,
                              void* d_out, int out_size, void* d_ws, size_t ws_size,
                              hipStream_t stream) {
  const float* logits = (const float*)d_in[0];
  const float* temps = (const float*)d_in[1];
  const int* topks = (const int*)d_in[2];
  const float* topps = (const float*)d_in[3];
  const float* noise = (const float*)d_in[4];
  int* out = (int*)d_out;
  const int B = in_sizes[1];
  const int V = in_sizes[0] / B;
  (void)n_in; (void)out_size; (void)ws_size;

  u32* w = (u32*)d_ws;
  size_t o = 0;
  u32* hist = w + o; o += (size_t)B * NB;
  u32* maxkey = w + o; o += B;
  u32* gcnt = w + o; o += B;
  u32* nm1 = w + o; o += 1;
  if (o & 1) o += 1;
  u64* rpack = (u64*)(w + o); o += 2 * (size_t)B;
  float* Sparts = (float*)(w + o); o += MAXM1 * SA;
  u32* m1c0 = w + o; o += (size_t)MAXM1 * NB;
  float* m1e0 = (float*)(w + o); o += (size_t)MAXM1 * NB;
  u32* m1c1 = w + o; o += (size_t)MAXM1 * NB;
  float* m1e1 = (float*)(w + o); o += (size_t)MAXM1 * NB;
  u32* m1c2 = w + o; o += (size_t)MAXM1 * 256;
  const size_t zwords = o;
  float* candv = (float*)(w + o); o += (size_t)B * GCAP;
  int* candi = (int*)(w + o); o += (size_t)B * GCAP;
  State* st = (State*)(w + o);

  kz<<<1024, 256, 0, stream>>>(w, zwords);
  kA<<<dim3(B, SA), TB, 0, stream>>>(logits, temps, hist, maxkey, V);
  kB<<<B, TB, 0, stream>>>(hist, topks, maxkey, st, nm1, V);
  kC<<<dim3(B, SA), TB, 0, stream>>>(logits, temps, st, Sparts, m1c0, m1e0, V);
  kC2<<<B, TB, 0, stream>>>(topps, Sparts, m1c0, m1e0, st);
  kD<<<dim3(B, SA), TB, 0, stream>>>(logits, temps, st, m1c1, m1e1, V);
  kD2<<<B, TB, 0, stream>>>(m1c1, m1e1, st);
  kE<<<dim3(B, SA), TB, 0, stream>>>(logits, temps, st, m1c2, V);
  kE2<<<B, TB, 0, stream>>>(topps, m1c2, st);
  kG<<<dim3(B, SA), TB, 0, stream>>>(logits, temps, st, gcnt, candv, candi, V);
  kH<<<B, TB, 0, stream>>>(topps, noise, gcnt, candv, candi, st, out, V);
  kI<<<dim3(B, SA), TB, 0, stream>>>(logits, temps, noise, st, rpack, V);
  kJ<<<(B + 255) / 256, 256, 0, stream>>>(st, rpack, out, B);
}

// Round 3
// 308.630 us; speedup vs baseline: 2.0505x; 1.3151x over previous
//
#include <hip/hip_runtime.h>
#include <math.h>

#define SA 8      /* segments for all-row kernels (kA, kG) */
#define SM 64     /* segments for mode-1 row kernels */
#define NB 4096
#define TB 256
#define CH (NB / TB) /* 16 */
#define GCAP 1024
#define MAXM1 16
#define EQC 64
#define FXS 1099511627776.0f /* 2^40 */
#define FXI (1.0f / 1099511627776.0f)

typedef unsigned u32;
typedef unsigned long long u64;

struct State {
  float m, S, target, Z2;
  int mode, k, cnt_above;
  float exp_above;
  u32 prefix, vstar;
  int m1, r, eqn;
  int eq[EQC];
};

struct ScanAux {
  u32 ccnt[TB]; float cesum[TB];
  u32 csufc[TB]; float csufe[TB];
  int candbin[TB]; u32 candca[TB]; float candea[TB];
  int fbbin[TB]; u32 fbca[TB]; float fbea[TB];
};

__device__ __forceinline__ u32 f2key(float f) {
  u32 u = __float_as_uint(f);
  return u ^ ((u >> 31) ? 0xFFFFFFFFu : 0x80000000u);
}
__device__ __forceinline__ float key2f(u32 k) {
  u32 u = (k & 0x80000000u) ? (k ^ 0x80000000u) : ~k;
  return __uint_as_float(u);
}

// proven-exact scan (R1/R2): find bin (descending) where cum count/exp crosses
__device__ void scan_select(const u32* cnt, const float* esum, ScanAux* ax,
                            State* rs, float S, float p, int level) {
  const int tid = threadIdx.x;
  const int mode = rs->mode;
  const u32 ca0 = (level == 0) ? 0u : (u32)rs->cnt_above;
  const float ea0 = (level == 0) ? 0.f : rs->exp_above;
  float target = 0.f;
  if (mode == 1) target = (level == 0) ? (p * S) : rs->target;
  const int need = (mode == 0) ? (rs->k - (int)ca0) : 0;

  {
    u32 cc = 0; float ce = 0.f;
    int base = tid * CH;
    for (int j = 0; j < CH; ++j) { cc += cnt[base + j]; ce += esum[base + j]; }
    ax->ccnt[tid] = cc; ax->cesum[tid] = ce;
  }
  __syncthreads();
  if (tid == 0) {
    u32 rc = 0; float re = 0.f;
    for (int c = TB - 1; c >= 0; --c) {
      ax->csufc[c] = rc; ax->csufe[c] = re;
      rc += ax->ccnt[c]; re += ax->cesum[c];
    }
  }
  __syncthreads();
  {
    int base = tid * CH;
    u32 rc = ax->csufc[tid]; float re = ax->csufe[tid];
    int best = -1; u32 bca = 0; float bea = 0.f;
    int fb = -1; u32 fca = 0; float fea = 0.f;
    for (int b = base + CH - 1; b >= base; --b) {
      u32 c = cnt[b];
      bool cross;
      if (mode == 0) cross = (c > 0) && ((int)(rc + c) >= need);
      else cross = (c > 0) && (ea0 + (re + esum[b]) >= target);
      if (cross && best < 0) { best = b; bca = rc; bea = re; }
      if (c > 0) { fb = b; fca = rc; fea = re; }
      rc += c; re += esum[b];
    }
    ax->candbin[tid] = best; ax->candca[tid] = bca; ax->candea[tid] = bea;
    ax->fbbin[tid] = fb; ax->fbca[tid] = fca; ax->fbea[tid] = fea;
  }
  __syncthreads();
  if (tid == 0) {
    int bsel = -1; u32 ca = 0; float ea = 0.f;
    for (int c = 0; c < TB; ++c) {
      int b = ax->candbin[c];
      if (b > bsel) { bsel = b; ca = ax->candca[c]; ea = ax->candea[c]; }
    }
    if (bsel < 0) {
      for (int c = 0; c < TB; ++c) {
        int b = ax->fbbin[c];
        if (b >= 0 && (bsel < 0 || b < bsel)) { bsel = b; ca = ax->fbca[c]; ea = ax->fbea[c]; }
      }
    }
    if (bsel < 0) bsel = 0;
    rs->prefix = (level == 0) ? (u32)bsel : ((rs->prefix << 12) | (u32)bsel);
    rs->cnt_above = (int)(ca0 + ca);
    rs->exp_above = ea0 + ea;
    rs->target = target;
  }
}

__global__ void kz(u32* __restrict__ w, size_t nwords) {
  size_t i = (size_t)blockIdx.x * blockDim.x + threadIdx.x;
  size_t stride = (size_t)gridDim.x * blockDim.x;
  for (; i < nwords; i += stride) w[i] = 0;
}

// fused: per-row max + 4096-bin count hist (integer atomics, run-length agg)
__global__ __launch_bounds__(TB) void kA(const float* __restrict__ logits,
                                         const float* __restrict__ temps,
                                         u32* __restrict__ hist,
                                         u32* __restrict__ maxkey, int V) {
  const int row = blockIdx.x, seg = blockIdx.y, tid = threadIdx.x;
  __shared__ u32 cnt[NB];
  __shared__ float sm[TB];
  for (int i = tid; i < NB; i += TB) cnt[i] = 0;
  __syncthreads();
  const float t = temps[row];
  const float* lr = logits + (size_t)row * V;
  const float4* l4 = (const float4*)lr;
  const int n4 = V >> 2;
  const int q0 = (int)((long long)seg * n4 / SA);
  const int q1 = (int)((long long)(seg + 1) * n4 / SA);
  float mx = -INFINITY;
  for (int i = q0 + tid; i < q1; i += TB) {
    float4 v = l4[i];
    float xs[4] = {v.x / t, v.y / t, v.z / t, v.w / t};
    u32 cur = 0xFFFFFFFFu, acc = 0;
#pragma unroll
    for (int j = 0; j < 4; ++j) {
      mx = fmaxf(mx, xs[j]);
      u32 b = f2key(xs[j]) >> 20;
      if (b == cur) acc++;
      else { if (acc) atomicAdd(&cnt[cur], acc); cur = b; acc = 1; }
    }
    if (acc) atomicAdd(&cnt[cur], acc);
  }
  if (seg == SA - 1)
    for (int i = (n4 << 2) + tid; i < V; i += TB) {
      float x = lr[i] / t;
      atomicAdd(&cnt[f2key(x) >> 20], 1u);
      mx = fmaxf(mx, x);
    }
  sm[tid] = mx;
  __syncthreads();
  for (int s = TB >> 1; s > 0; s >>= 1) {
    if (tid < s) sm[tid] = fmaxf(sm[tid], sm[tid + s]);
    __syncthreads();
  }
  if (tid == 0) atomicMax(&maxkey[row], f2key(sm[0]));
  for (int b = tid; b < NB; b += TB) {
    u32 c = cnt[b];
    if (c) atomicAdd(&hist[(size_t)row * NB + b], c);
  }
}

// per-row: mode decision + mode-0 level-0 crossing bin; compact mode-1 rows
__global__ __launch_bounds__(TB) void kB(const u32* __restrict__ hist,
                                         const int* __restrict__ topks,
                                         const u32* __restrict__ maxkey,
                                         State* __restrict__ st,
                                         u32* __restrict__ nm1,
                                         u32* __restrict__ m1rows, int V) {
  const int row = blockIdx.x, tid = threadIdx.x;
  State* rs = &st[row];
  __shared__ u32 h[NB];
  __shared__ u32 cs[TB];
  __shared__ int bb[TB];
  for (int i = tid; i < NB; i += TB) h[i] = hist[(size_t)row * NB + i];
  __syncthreads();
  int k = topks[row];
  int mode = (k >= 1 && k < V) ? 0 : 1;
  if (tid == 0) {
    rs->m = key2f(maxkey[row]);
    rs->mode = mode; rs->k = k;
    rs->eqn = 0; rs->r = 0;
    if (mode == 1) {
      int idx = (int)atomicAdd(nm1, 1u);
      rs->m1 = idx;
      if (idx < MAXM1) m1rows[idx] = (u32)row;
    }
  }
  u32 cc = 0;
  const int base = tid * CH;
  for (int j = 0; j < CH; ++j) cc += h[base + j];
  cs[tid] = cc;
  __syncthreads();
  if (tid == 0) {
    u32 rc = 0;
    for (int c = TB - 1; c >= 0; --c) { u32 t2 = cs[c]; cs[c] = rc; rc += t2; }
  }
  __syncthreads();
  {
    u32 rc = cs[tid];
    int best = -1;
    for (int b = base + CH - 1; b >= base; --b) {
      u32 c = h[b];
      if (c && best < 0 && (int)(rc + c) >= k) best = b;
      rc += c;
    }
    bb[tid] = best;
  }
  __syncthreads();
  if (tid == 0 && mode == 0) {
    int bsel = -1;
    for (int c = 0; c < TB; ++c) if (bb[c] > bsel) bsel = bb[c];
    if (bsel < 0) { for (int b2 = 0; b2 < NB; ++b2) if (h[b2]) { bsel = b2; break; } }
    if (bsel < 0) bsel = 0;
    rs->vstar = ((u32)bsel) << 20;  // mode-0 gather threshold T0
  }
}

// mode-1: level-0 count + fixed-point esum hist + S partials (integer atomics)
__global__ __launch_bounds__(TB) void kC(const float* __restrict__ logits,
                                         const float* __restrict__ temps,
                                         const State* __restrict__ st,
                                         const u32* __restrict__ nm1,
                                         const u32* __restrict__ m1rows,
                                         float* __restrict__ Sparts,
                                         u32* __restrict__ m1c0,
                                         u64* __restrict__ m1e0, int V) {
  u32 n = nm1[0]; if (n > MAXM1) n = MAXM1;
  if (blockIdx.x >= n) return;
  const int row = (int)m1rows[blockIdx.x];
  const int m1 = blockIdx.x, seg = blockIdx.y, tid = threadIdx.x;
  const State* rs = &st[row];
  __shared__ u32 c0[NB];
  __shared__ u64 e0[NB];
  __shared__ float ss[TB];
  for (int i = tid; i < NB; i += TB) { c0[i] = 0; e0[i] = 0ull; }
  __syncthreads();
  const float t = temps[row];
  const float m = rs->m;
  const float* lr = logits + (size_t)row * V;
  const float4* l4 = (const float4*)lr;
  const int n4 = V >> 2;
  const int q0 = (int)((long long)seg * n4 / SM);
  const int q1 = (int)((long long)(seg + 1) * n4 / SM);
  float ls = 0.f;
  for (int i = q0 + tid; i < q1; i += TB) {
    float4 v = l4[i];
    float xs[4] = {v.x / t, v.y / t, v.z / t, v.w / t};
    u32 cur = 0xFFFFFFFFu, acc = 0; u64 afx = 0ull;
#pragma unroll
    for (int j = 0; j < 4; ++j) {
      float x = xs[j];
      float e = expf(x - m);
      ls += e;
      u32 b = f2key(x) >> 20;
      u64 fx = (u64)(e * FXS);
      if (b == cur) { acc++; afx += fx; }
      else {
        if (acc) { atomicAdd(&c0[cur], acc); if (afx) atomicAdd(&e0[cur], afx); }
        cur = b; acc = 1; afx = fx;
      }
    }
    if (acc) { atomicAdd(&c0[cur], acc); if (afx) atomicAdd(&e0[cur], afx); }
  }
  if (seg == SM - 1)
    for (int i = (n4 << 2) + tid; i < V; i += TB) {
      float x = lr[i] / t;
      float e = expf(x - m);
      ls += e;
      atomicAdd(&c0[f2key(x) >> 20], 1u);
      u64 fx = (u64)(e * FXS);
      if (fx) atomicAdd(&e0[f2key(x) >> 20], fx);
    }
  ss[tid] = ls;
  __syncthreads();
  for (int s = TB >> 1; s > 0; s >>= 1) {
    if (tid < s) ss[tid] += ss[tid + s];
    __syncthreads();
  }
  if (tid == 0) Sparts[m1 * SM + seg] = ss[0];
  for (int b = tid; b < NB; b += TB) {
    if (c0[b]) atomicAdd(&m1c0[(size_t)m1 * NB + b], c0[b]);
    if (e0[b]) atomicAdd(&m1e0[(size_t)m1 * NB + b], e0[b]);
  }
}

__global__ __launch_bounds__(TB) void kC2(const float* __restrict__ topps,
                                          const u32* __restrict__ nm1,
                                          const u32* __restrict__ m1rows,
                                          const float* __restrict__ Sparts,
                                          const u32* __restrict__ m1c0,
                                          const u64* __restrict__ m1e0,
                                          State* __restrict__ st) {
  u32 n = nm1[0]; if (n > MAXM1) n = MAXM1;
  if (blockIdx.x >= n) return;
  const int row = (int)m1rows[blockIdx.x];
  const int m1 = blockIdx.x, tid = threadIdx.x;
  State* rs = &st[row];
  __shared__ u32 cnt[NB];
  __shared__ float esum[NB];
  __shared__ ScanAux ax;
  for (int i = tid; i < NB; i += TB) {
    cnt[i] = m1c0[(size_t)m1 * NB + i];
    esum[i] = (float)m1e0[(size_t)m1 * NB + i] * FXI;
  }
  __syncthreads();
  float S = 0.f;
  for (int j = 0; j < SM; ++j) S += Sparts[m1 * SM + j];
  if (tid == 0) rs->S = S;
  scan_select(cnt, esum, &ax, rs, S, topps[row], 0);
}

// mode-1: level-1 (middle 12 bits), fixed-point esum
__global__ __launch_bounds__(TB) void kD(const float* __restrict__ logits,
                                         const float* __restrict__ temps,
                                         const State* __restrict__ st,
                                         const u32* __restrict__ nm1,
                                         const u32* __restrict__ m1rows,
                                         u32* __restrict__ m1c1,
                                         u64* __restrict__ m1e1, int V) {
  u32 n = nm1[0]; if (n > MAXM1) n = MAXM1;
  if (blockIdx.x >= n) return;
  const int row = (int)m1rows[blockIdx.x];
  const int m1 = blockIdx.x, seg = blockIdx.y, tid = threadIdx.x;
  const State* rs = &st[row];
  __shared__ u32 c1[NB];
  __shared__ u64 e1[NB];
  for (int i = tid; i < NB; i += TB) { c1[i] = 0; e1[i] = 0ull; }
  __syncthreads();
  const float t = temps[row];
  const float m = rs->m;
  const u32 pfx = rs->prefix;  // 12-bit
  const float* lr = logits + (size_t)row * V;
  const float4* l4 = (const float4*)lr;
  const int n4 = V >> 2;
  const int q0 = (int)((long long)seg * n4 / SM);
  const int q1 = (int)((long long)(seg + 1) * n4 / SM);
  for (int i = q0 + tid; i < q1; i += TB) {
    float4 v = l4[i];
    float xs[4] = {v.x / t, v.y / t, v.z / t, v.w / t};
#pragma unroll
    for (int j = 0; j < 4; ++j) {
      u32 key = f2key(xs[j]);
      if ((key >> 20) == pfx) {
        float e = expf(xs[j] - m);
        atomicAdd(&c1[(key >> 8) & 0xFFFu], 1u);
        u64 fx = (u64)(e * FXS);
        if (fx) atomicAdd(&e1[(key >> 8) & 0xFFFu], fx);
      }
    }
  }
  if (seg == SM - 1)
    for (int i = (n4 << 2) + tid; i < V; i += TB) {
      float x = lr[i] / t;
      u32 key = f2key(x);
      if ((key >> 20) == pfx) {
        float e = expf(x - m);
        atomicAdd(&c1[(key >> 8) & 0xFFFu], 1u);
        u64 fx = (u64)(e * FXS);
        if (fx) atomicAdd(&e1[(key >> 8) & 0xFFFu], fx);
      }
    }
  __syncthreads();
  for (int b = tid; b < NB; b += TB) {
    if (c1[b]) atomicAdd(&m1c1[(size_t)m1 * NB + b], c1[b]);
    if (e1[b]) atomicAdd(&m1e1[(size_t)m1 * NB + b], e1[b]);
  }
}

__global__ __launch_bounds__(TB) void kD2(const u32* __restrict__ nm1,
                                          const u32* __restrict__ m1rows,
                                          const u32* __restrict__ m1c1,
                                          const u64* __restrict__ m1e1,
                                          State* __restrict__ st) {
  u32 n = nm1[0]; if (n > MAXM1) n = MAXM1;
  if (blockIdx.x >= n) return;
  const int row = (int)m1rows[blockIdx.x];
  const int m1 = blockIdx.x, tid = threadIdx.x;
  State* rs = &st[row];
  __shared__ u32 cnt[NB];
  __shared__ float esum[NB];
  __shared__ ScanAux ax;
  for (int i = tid; i < NB; i += TB) {
    cnt[i] = m1c1[(size_t)m1 * NB + i];
    esum[i] = (float)m1e1[(size_t)m1 * NB + i] * FXI;
  }
  __syncthreads();
  scan_select(cnt, esum, &ax, rs, rs->S, 0.f, 1);
}

// mode-1: final 8-bit count hist
__global__ __launch_bounds__(TB) void kE(const float* __restrict__ logits,
                                         const float* __restrict__ temps,
                                         const State* __restrict__ st,
                                         const u32* __restrict__ nm1,
                                         const u32* __restrict__ m1rows,
                                         u32* __restrict__ m1c2, int V) {
  u32 n = nm1[0]; if (n > MAXM1) n = MAXM1;
  if (blockIdx.x >= n) return;
  const int row = (int)m1rows[blockIdx.x];
  const int m1 = blockIdx.x, seg = blockIdx.y, tid = threadIdx.x;
  const State* rs = &st[row];
  __shared__ u32 c2[256];
  c2[tid] = 0;
  __syncthreads();
  const float t = temps[row];
  const u32 pfx = rs->prefix;  // 24-bit
  const float* lr = logits + (size_t)row * V;
  const float4* l4 = (const float4*)lr;
  const int n4 = V >> 2;
  const int q0 = (int)((long long)seg * n4 / SM);
  const int q1 = (int)((long long)(seg + 1) * n4 / SM);
  for (int i = q0 + tid; i < q1; i += TB) {
    float4 v = l4[i];
    float xs[4] = {v.x / t, v.y / t, v.z / t, v.w / t};
#pragma unroll
    for (int j = 0; j < 4; ++j) {
      u32 key = f2key(xs[j]);
      if ((key >> 8) == pfx) atomicAdd(&c2[key & 0xFFu], 1u);
    }
  }
  if (seg == SM - 1)
    for (int i = (n4 << 2) + tid; i < V; i += TB) {
      u32 key = f2key(lr[i] / t);
      if ((key >> 8) == pfx) atomicAdd(&c2[key & 0xFFu], 1u);
    }
  __syncthreads();
  if (c2[tid]) atomicAdd(&m1c2[(size_t)m1 * 256 + tid], c2[tid]);
}

// mode-1: exact per-copy cumsum replay (parallel expf precompute, serial replay)
__global__ __launch_bounds__(TB) void kE2(const float* __restrict__ topps,
                                          const u32* __restrict__ nm1,
                                          const u32* __restrict__ m1rows,
                                          const u32* __restrict__ m1c2,
                                          State* __restrict__ st) {
  u32 n = nm1[0]; if (n > MAXM1) n = MAXM1;
  if (blockIdx.x >= n) return;
  const int row = (int)m1rows[blockIdx.x];
  const int m1 = blockIdx.x, tid = threadIdx.x;
  State* rs = &st[row];
  __shared__ float eb[256], enb[256];
  __shared__ u32 cb[256];
  const u32 pfx = rs->prefix;
  const float m = rs->m;
  const float S = rs->S;
  {
    u32 key = (pfx << 8) | (u32)tid;
    float v = key2f(key);
    float e = expf(v - m);
    eb[tid] = e; enb[tid] = e / S;
    cb[tid] = m1c2[(size_t)m1 * 256 + tid];
  }
  __syncthreads();
  if (tid != 0) return;
  const float p = topps[row];
  float run_n = rs->exp_above / S;
  float run_u = rs->exp_above;
  const int have_above = (rs->cnt_above > 0);
  u32 lastkey = 0u; int lastr = 0; int anykept = 0;
  u32 vsel = 0u; int rsel = -1;
  for (int b = 255; b >= 0; --b) {
    int c = (int)cb[b];
    if (c == 0) continue;
    u32 key = (pfx << 8) | (u32)b;
    float e = eb[b];
    float en = enb[b];
    int kept = 0;
    for (int q = 0; q < c; ++q) {
      float nn = run_n + en;
      if (nn < p) { run_n = nn; run_u += e; kept++; } else break;
    }
    if (kept == c) { lastkey = key; lastr = c; anykept = 1; continue; }
    if (kept > 0) { vsel = key; rsel = kept; }
    else if (anykept) { vsel = lastkey; rsel = lastr; }
    else if (have_above) { vsel = key; rsel = 0; }
    else { vsel = key; rsel = 1; run_u += e; }
    break;
  }
  if (rsel < 0) {
    if (anykept) { vsel = lastkey; rsel = lastr; }
    else { vsel = (pfx << 8); rsel = have_above ? 0 : 1; }
  }
  rs->vstar = vsel; rs->r = rsel; rs->Z2 = run_u;
}

// gather candidates: mode-0 key >= T0; mode-1 key == vstar
__global__ __launch_bounds__(TB) void kG(const float* __restrict__ logits,
                                         const float* __restrict__ temps,
                                         const State* __restrict__ st,
                                         u32* __restrict__ gcnt,
                                         float* __restrict__ candv,
                                         int* __restrict__ candi, int V) {
  const int row = blockIdx.x, seg = blockIdx.y, tid = threadIdx.x;
  const State* rs = &st[row];
  const int mode = rs->mode;
  const u32 vk = rs->vstar;
  const float t = temps[row];
  const float* lr = logits + (size_t)row * V;
  const float4* l4 = (const float4*)lr;
  const int n4 = V >> 2;
  const int q0 = (int)((long long)seg * n4 / SA);
  const int q1 = (int)((long long)(seg + 1) * n4 / SA);
  for (int i = q0 + tid; i < q1; i += TB) {
    float4 v = l4[i];
    float xs[4] = {v.x / t, v.y / t, v.z / t, v.w / t};
#pragma unroll
    for (int j = 0; j < 4; ++j) {
      u32 key = f2key(xs[j]);
      bool take = (mode == 0) ? (key >= vk) : (key == vk);
      if (take) {
        u32 slot = atomicAdd(&gcnt[row], 1u);
        if (slot < GCAP) {
          candv[(size_t)row * GCAP + slot] = xs[j];
          candi[(size_t)row * GCAP + slot] = i * 4 + j;
        }
      }
    }
  }
  if (seg == SA - 1)
    for (int i = (n4 << 2) + tid; i < V; i += TB) {
      float x = lr[i] / t;
      u32 key = f2key(x);
      bool take = (mode == 0) ? (key >= vk) : (key == vk);
      if (take) {
        u32 slot = atomicAdd(&gcnt[row], 1u);
        if (slot < GCAP) {
          candv[(size_t)row * GCAP + slot] = x;
          candi[(size_t)row * GCAP + slot] = i;
        }
      }
    }
}

// solve: exact reference replay on sorted candidates; mode-0 runs the race here
__global__ __launch_bounds__(TB) void kH(const float* __restrict__ topps,
                                         const float* __restrict__ noise,
                                         const u32* __restrict__ gcnt,
                                         const float* __restrict__ candv,
                                         const int* __restrict__ candi,
                                         State* __restrict__ st,
                                         int* __restrict__ out, int V) {
  const int row = blockIdx.x, tid = threadIdx.x;
  State* rs = &st[row];
  __shared__ float gv[GCAP]; __shared__ int gi[GCAP];
  __shared__ float sv[GCAP]; __shared__ int si[GCAP];
  __shared__ float rr[TB]; __shared__ int ri[TB];
  __shared__ int sJ; __shared__ float sZ2;
  int g = (int)gcnt[row]; if (g > GCAP) g = GCAP;
  for (int i = tid; i < g; i += TB) {
    gv[i] = candv[(size_t)row * GCAP + i];
    gi[i] = candi[(size_t)row * GCAP + i];
  }
  __syncthreads();
  // rank sort by (value desc, index asc) == stable argsort(-x)
  for (int i = tid; i < g; i += TB) {
    float v = gv[i]; int ix = gi[i];
    int rank = 0;
    for (int j = 0; j < g; ++j) {
      float vj = gv[j]; int ij = gi[j];
      if (vj > v || (vj == v && ij < ix)) rank++;
    }
    sv[rank] = v; si[rank] = ix;
  }
  __syncthreads();
  const float m = rs->m;
  const float p = topps[row];
  if (rs->mode == 0) {
    if (tid == 0) {
      int keff = rs->k; if (keff > g) keff = g;
      int J = 1; float Z2 = 1.f;
      if (g > 0 && keff > 0) {
        float Zk = 0.f;
        for (int j = 0; j < keff; ++j) Zk += expf(sv[j] - m);
        float c = 0.f; J = 0;
        for (int j = 0; j < keff; ++j) {
          float pr = expf(sv[j] - m) / Zk;
          c += pr;
          if (c < p) J++; else break;
        }
        if (J < 1) J = 1;
        Z2 = 0.f;
        for (int j = 0; j < J; ++j) Z2 += expf(sv[j] - m);
      }
      sJ = J; sZ2 = Z2;
    }
    __syncthreads();
    const int J = sJ; const float Z2 = sZ2;
    float best = -1.f; int bidx = 0x7FFFFFFF;
    for (int j = tid; j < J && j < g; j += TB) {
      int ix = si[j];
      float u = noise[(size_t)row * V + ix];
      float q = fmaxf(-logf(u), 1e-10f);
      float pr = expf(sv[j] - m) / Z2;
      float rt = pr / q;
      if (rt > best || (rt == best && ix < bidx)) { best = rt; bidx = ix; }
    }
    rr[tid] = best; ri[tid] = bidx;
    __syncthreads();
    for (int s = TB >> 1; s > 0; s >>= 1) {
      if (tid < s) {
        float ov = rr[tid + s]; int oi = ri[tid + s];
        if (ov > rr[tid] || (ov == rr[tid] && oi < ri[tid])) { rr[tid] = ov; ri[tid] = oi; }
      }
      __syncthreads();
    }
    if (tid == 0) out[row] = ri[0];
  } else {
    if (tid == 0) {
      int eqn = rs->r;
      if (eqn > g) eqn = g;
      if (eqn > EQC) eqn = EQC;
      if (eqn < 0) eqn = 0;
      for (int j = 0; j < eqn; ++j) rs->eq[j] = si[j];  // idx asc among equal values
      rs->eqn = eqn;
    }
  }
}

// mode-1: race over full row, packed (ratio_key, ~idx) atomicMax
__global__ __launch_bounds__(TB) void kI(const float* __restrict__ logits,
                                         const float* __restrict__ temps,
                                         const float* __restrict__ noise,
                                         const State* __restrict__ st,
                                         const u32* __restrict__ nm1,
                                         const u32* __restrict__ m1rows,
                                         u64* __restrict__ rpack, int V) {
  u32 n = nm1[0]; if (n > MAXM1) n = MAXM1;
  if (blockIdx.x >= n) return;
  const int row = (int)m1rows[blockIdx.x];
  const int seg = blockIdx.y, tid = threadIdx.x;
  const State* rs = &st[row];
  __shared__ int eqs[EQC]; __shared__ int seqn;
  __shared__ float rr[TB]; __shared__ int ri[TB];
  if (tid == 0) {
    int nn = rs->eqn; if (nn > EQC) nn = EQC; if (nn < 0) nn = 0;
    seqn = nn;
    for (int i = 0; i < nn; ++i) eqs[i] = rs->eq[i];
  }
  __syncthreads();
  const float t = temps[row];
  const float m = rs->m;
  const float Z2 = rs->Z2;
  const u32 vk = rs->vstar;
  const int eqn = seqn;
  const float* lr = logits + (size_t)row * V;
  const float* ur = noise + (size_t)row * V;
  const float4* l4 = (const float4*)lr;
  const float4* u4 = (const float4*)ur;
  const int n4 = V >> 2;
  const int q0 = (int)((long long)seg * n4 / SM);
  const int q1 = (int)((long long)(seg + 1) * n4 / SM);
  float best = -1.f; int bidx = 0x7FFFFFFF;
  for (int i = q0 + tid; i < q1; i += TB) {
    float4 xv = l4[i];
    float4 uv = u4[i];
    float xs[4] = {xv.x / t, xv.y / t, xv.z / t, xv.w / t};
    float us[4] = {uv.x, uv.y, uv.z, uv.w};
#pragma unroll
    for (int j = 0; j < 4; ++j) {
      u32 key = f2key(xs[j]);
      bool kept = key > vk;
      if (!kept && key == vk) {
        int idx = i * 4 + j;
        for (int e = 0; e < eqn; ++e) if (eqs[e] == idx) { kept = true; break; }
      }
      if (kept) {
        float pr = expf(xs[j] - m) / Z2;
        float q = fmaxf(-logf(us[j]), 1e-10f);
        float rt = pr / q;
        int idx = i * 4 + j;
        if (rt > best || (rt == best && idx < bidx)) { best = rt; bidx = idx; }
      }
    }
  }
  if (seg == SM - 1)
    for (int i = (n4 << 2) + tid; i < V; i += TB) {
      float x = lr[i] / t;
      u32 key = f2key(x);
      bool kept = key > vk;
      if (!kept && key == vk) {
        for (int e = 0; e < eqn; ++e) if (eqs[e] == i) { kept = true; break; }
      }
      if (kept) {
        float pr = expf(x - m) / Z2;
        float q = fmaxf(-logf(ur[i]), 1e-10f);
        float rt = pr / q;
        if (rt > best || (rt == best && i < bidx)) { best = rt; bidx = i; }
      }
    }
  rr[tid] = best; ri[tid] = bidx;
  __syncthreads();
  for (int s = TB >> 1; s > 0; s >>= 1) {
    if (tid < s) {
      float ov = rr[tid + s]; int oi = ri[tid + s];
      if (ov > rr[tid] || (ov == rr[tid] && oi < ri[tid])) { rr[tid] = ov; ri[tid] = oi; }
    }
    __syncthreads();
  }
  if (tid == 0 && rr[0] >= 0.f) {
    u64 pk = ((u64)f2key(rr[0]) << 32) | (u64)(0xFFFFFFFFu - (u32)ri[0]);
    atomicMax(&rpack[row], pk);
  }
}

__global__ void kJ(const State* __restrict__ st, const u64* __restrict__ rpack,
                   int* __restrict__ out, int B) {
  int i = blockIdx.x * blockDim.x + threadIdx.x;
  if (i < B && st[i].mode == 1)
    out[i] = (int)(0xFFFFFFFFu - (u32)(rpack[i] & 0xFFFFFFFFull));
}

extern "C" void kernel_launch(void* const* d_in, const int* in_sizes, int n_in,
                              void* d_out, int out_size, void* d_ws, size_t ws_size,
                              hipStream_t stream) {
  const float* logits = (const float*)d_in[0];
  const float* temps = (const float*)d_in[1];
  const int* topks = (const int*)d_in[2];
  const float* topps = (const float*)d_in[3];
  const float* noise = (const float*)d_in[4];
  int* out = (int*)d_out;
  const int B = in_sizes[1];
  const int V = in_sizes[0] / B;
  (void)n_in; (void)out_size; (void)ws_size;

  u32* w = (u32*)d_ws;
  size_t o = 0;
  u32* hist = w + o; o += (size_t)B * NB;
  u32* maxkey = w + o; o += B;
  u32* gcnt = w + o; o += B;
  u32* nm1 = w + o; o += 1;
  u32* m1rows = w + o; o += MAXM1;
  if (o & 1) o += 1;
  u64* rpack = (u64*)(w + o); o += 2 * (size_t)B;
  float* Sparts = (float*)(w + o); o += (size_t)MAXM1 * SM;
  u32* m1c0 = w + o; o += (size_t)MAXM1 * NB;
  u64* m1e0 = (u64*)(w + o); o += 2 * (size_t)MAXM1 * NB;
  u32* m1c1 = w + o; o += (size_t)MAXM1 * NB;
  u64* m1e1 = (u64*)(w + o); o += 2 * (size_t)MAXM1 * NB;
  u32* m1c2 = w + o; o += (size_t)MAXM1 * 256;
  const size_t zwords = o;
  float* candv = (float*)(w + o); o += (size_t)B * GCAP;
  int* candi = (int*)(w + o); o += (size_t)B * GCAP;
  State* st = (State*)(w + o);

  kz<<<1024, 256, 0, stream>>>(w, zwords);
  kA<<<dim3(B, SA), TB, 0, stream>>>(logits, temps, hist, maxkey, V);
  kB<<<B, TB, 0, stream>>>(hist, topks, maxkey, st, nm1, m1rows, V);
  kC<<<dim3(MAXM1, SM), TB, 0, stream>>>(logits, temps, st, nm1, m1rows, Sparts, m1c0, m1e0, V);
  kC2<<<MAXM1, TB, 0, stream>>>(topps, nm1, m1rows, Sparts, m1c0, m1e0, st);
  kD<<<dim3(MAXM1, SM), TB, 0, stream>>>(logits, temps, st, nm1, m1rows, m1c1, m1e1, V);
  kD2<<<MAXM1, TB, 0, stream>>>(nm1, m1rows, m1c1, m1e1, st);
  kE<<<dim3(MAXM1, SM), TB, 0, stream>>>(logits, temps, st, nm1, m1rows, m1c2, V);
  kE2<<<MAXM1, TB, 0, stream>>>(topps, nm1, m1rows, m1c2, st);
  kG<<<dim3(B, SA), TB, 0, stream>>>(logits, temps, st, gcnt, candv, candi, V);
  kH<<<B, TB, 0, stream>>>(topps, noise, gcnt, candv, candi, st, out, V);
  kI<<<dim3(MAXM1, SM), TB, 0, stream>>>(logits, temps, noise, st, nm1, m1rows, rpack, V);
  kJ<<<(B + 255) / 256, 256, 0, stream>>>(st, rpack, out, B);
}